// Round 10
// baseline (438.153 us; speedup 1.0000x reference)
//
#include <hip/hip_runtime.h>
#include <hip/hip_cooperative_groups.h>
namespace cg = cooperative_groups;

#define B_   16
#define T_   256
#define V_   10000
#define C_   4096
#define NC_  128
#define CAP_ 224
#define MST  33    // LDS fp32 matrix stride (32+1)
#define XST  257   // LDS fp32 slab stride
#define HST  264   // LDS bf16 slab stride
#define SMEM_BYTES 51840

typedef __bf16 bf16x8 __attribute__((ext_vector_type(8)));
typedef unsigned short u16x8 __attribute__((ext_vector_type(8)));
typedef float  f32x4  __attribute__((ext_vector_type(4)));

__device__ inline unsigned short f2bf(float f){
  unsigned int u = __float_as_uint(f);
  u += 0x7FFFu + ((u >> 16) & 1u);
  return (unsigned short)(u >> 16);
}
__device__ inline float bf2f(unsigned short u){
  return __uint_as_float(((unsigned int)u) << 16);
}
__device__ inline f32x4 mfma16(bf16x8 a, bf16x8 b, f32x4 c){
  return __builtin_amdgcn_mfma_f32_16x16x32_bf16(a, b, c, 0, 0, 0);
}
__device__ inline bf16x8 load_cvt8(const float* p){
  u16x8 u;
  #pragma unroll
  for (int i = 0; i < 8; ++i) u[i] = f2bf(p[i]);
  return __builtin_bit_cast(bf16x8, u);
}
__device__ inline void zero_acc(f32x4 acc[2][4]){
  #pragma unroll
  for (int i = 0; i < 2; ++i)
    #pragma unroll
    for (int jx = 0; jx < 4; ++jx) acc[i][jx] = (f32x4){0.f,0.f,0.f,0.f};
}

// fx accumulators in Afx: A0,A1,A2,A3 (4 x 256 floats)
__device__ inline void fx_accum(const float* __restrict__ W, const float* xh,
                                int j, float* __restrict__ Anext){
  int t = threadIdx.x;
  float p = 0.f;
  #pragma unroll
  for (int i = 0; i < 8; ++i)
    p = fmaf(xh[i], W[(size_t)(8*j + i)*256 + t], p);
  atomicAdd(&Anext[t], p);
}

// ===========================================================================
// GEMM cores (32-row slab x 256 cols)
__device__ inline void mm_A_gf32(const float* __restrict__ A, size_t lda_row0,
    const unsigned short* __restrict__ Bt, int w, int ln, f32x4 acc[2][4]){
  int m16 = ln & 15, q = ln >> 4, c0 = w*64;
  const float* a0 = A + lda_row0 + (size_t)m16*256 + q*8;
  const float* a1 = a0 + 16*256;
  const unsigned short* bp0 = Bt + (size_t)(c0 + m16)*256 + q*8;
  #pragma unroll
  for (int kt = 0; kt < 8; ++kt){
    bf16x8 af0 = load_cvt8(a0 + kt*32);
    bf16x8 af1 = load_cvt8(a1 + kt*32);
    #pragma unroll
    for (int cj = 0; cj < 4; ++cj){
      bf16x8 bfj = *(const bf16x8*)(bp0 + (size_t)cj*16*256 + kt*32);
      acc[0][cj] = mfma16(af0, bfj, acc[0][cj]);
      acc[1][cj] = mfma16(af1, bfj, acc[1][cj]);
    }
  }
}

__device__ inline void mm_A_ldsbf(const unsigned short* sHb,
    const unsigned short* __restrict__ Bt, int w, int ln, f32x4 acc[2][4]){
  int m16 = ln & 15, q = ln >> 4, c0 = w*64;
  const unsigned short* a0 = sHb + m16*HST + q*8;
  const unsigned short* a1 = sHb + (16 + m16)*HST + q*8;
  const unsigned short* bp0 = Bt + (size_t)(c0 + m16)*256 + q*8;
  #pragma unroll
  for (int kt = 0; kt < 8; ++kt){
    bf16x8 af0 = *(const bf16x8*)(a0 + kt*32);
    bf16x8 af1 = *(const bf16x8*)(a1 + kt*32);
    #pragma unroll
    for (int cj = 0; cj < 4; ++cj){
      bf16x8 bfj = *(const bf16x8*)(bp0 + (size_t)cj*16*256 + kt*32);
      acc[0][cj] = mfma16(af0, bfj, acc[0][cj]);
      acc[1][cj] = mfma16(af1, bfj, acc[1][cj]);
    }
  }
}

__device__ inline void mm_A_ldsf32(const float* sX,
    const unsigned short* __restrict__ Bt, int w, int ln, f32x4 acc[2][4],
    float* lnrm){
  int m16 = ln & 15, q = ln >> 4, c0 = w*64;
  const float* a0 = sX + m16*XST + q*8;
  const float* a1 = sX + (16 + m16)*XST + q*8;
  const unsigned short* bp0 = Bt + (size_t)(c0 + m16)*256 + q*8;
  float ss0 = 0.f, ss1 = 0.f;
  #pragma unroll
  for (int kt = 0; kt < 8; ++kt){
    float av0[8], av1[8];
    #pragma unroll
    for (int i2 = 0; i2 < 8; ++i2){ av0[i2] = a0[kt*32 + i2]; av1[i2] = a1[kt*32 + i2]; }
    u16x8 u0, u1;
    #pragma unroll
    for (int i2 = 0; i2 < 8; ++i2){
      u0[i2] = f2bf(av0[i2]); u1[i2] = f2bf(av1[i2]);
      ss0 = fmaf(av0[i2], av0[i2], ss0);
      ss1 = fmaf(av1[i2], av1[i2], ss1);
    }
    bf16x8 af0 = __builtin_bit_cast(bf16x8, u0);
    bf16x8 af1 = __builtin_bit_cast(bf16x8, u1);
    #pragma unroll
    for (int cj = 0; cj < 4; ++cj){
      bf16x8 bfj = *(const bf16x8*)(bp0 + (size_t)cj*16*256 + kt*32);
      acc[0][cj] = mfma16(af0, bfj, acc[0][cj]);
      acc[1][cj] = mfma16(af1, bfj, acc[1][cj]);
    }
  }
  if (lnrm){
    ss0 += __shfl_xor(ss0, 16); ss0 += __shfl_xor(ss0, 32);
    ss1 += __shfl_xor(ss1, 16); ss1 += __shfl_xor(ss1, 32);
    if (w == 0 && q == 0){ lnrm[m16] = 0.5f*ss0; lnrm[16 + m16] = 0.5f*ss1; }
  }
}

// phi core from global fp32 A (row-clamped), with norm
__device__ inline void phi_core(const float* __restrict__ A,
    const unsigned short* __restrict__ Bt, int r0, int M, int w, int ln,
    f32x4 acc[2][4], float* lnrm)
{
  int m16 = ln & 15, q = ln >> 4;
  int c0 = w*64;
  int ra0 = r0 + m16;      if (ra0 > M-1) ra0 = M-1;
  int ra1 = r0 + 16 + m16; if (ra1 > M-1) ra1 = M-1;
  const float* a0 = A + (size_t)ra0*256 + q*8;
  const float* a1 = A + (size_t)ra1*256 + q*8;
  const unsigned short* bp0 = Bt + (size_t)(c0 + m16)*256 + q*8;
  float ss0 = 0.f, ss1 = 0.f;
  #pragma unroll
  for (int kt = 0; kt < 8; ++kt){
    float av0[8], av1[8];
    #pragma unroll
    for (int i2 = 0; i2 < 8; ++i2){ av0[i2] = a0[kt*32 + i2]; av1[i2] = a1[kt*32 + i2]; }
    u16x8 u0, u1;
    #pragma unroll
    for (int i2 = 0; i2 < 8; ++i2){
      u0[i2] = f2bf(av0[i2]); u1[i2] = f2bf(av1[i2]);
      ss0 = fmaf(av0[i2], av0[i2], ss0);
      ss1 = fmaf(av1[i2], av1[i2], ss1);
    }
    bf16x8 af0 = __builtin_bit_cast(bf16x8, u0);
    bf16x8 af1 = __builtin_bit_cast(bf16x8, u1);
    #pragma unroll
    for (int cj = 0; cj < 4; ++cj){
      bf16x8 bfj = *(const bf16x8*)(bp0 + (size_t)cj*16*256 + kt*32);
      acc[0][cj] = mfma16(af0, bfj, acc[0][cj]);
      acc[1][cj] = mfma16(af1, bfj, acc[1][cj]);
    }
  }
  ss0 += __shfl_xor(ss0, 16); ss0 += __shfl_xor(ss0, 32);
  ss1 += __shfl_xor(ss1, 16); ss1 += __shfl_xor(ss1, 32);
  if (w == 0 && q == 0){ lnrm[m16] = 0.5f*ss0; lnrm[16 + m16] = 0.5f*ss1; }
}

// ===========================================================================
__device__ inline void dev_phiB(const float* __restrict__ A,
    const unsigned short* __restrict__ projT, unsigned short* __restrict__ Ebp,
    float* __restrict__ S, int r0, float* lnrm)
{
  int tid = threadIdx.x;
  int w = tid >> 6, ln = tid & 63;
  int m16 = ln & 15, q = ln >> 4;
  f32x4 acc[2][4];
  zero_acc(acc);
  phi_core(A, projT, r0, C_, w, ln, acc, lnrm);
  __syncthreads();
  int c0 = w*64;
  #pragma unroll
  for (int cj = 0; cj < 4; ++cj){
    int col = c0 + cj*16 + m16;
    float cs = 0.f;
    #pragma unroll
    for (int ri = 0; ri < 2; ++ri){
      #pragma unroll
      for (int r = 0; r < 4; ++r){
        int row = ri*16 + q*4 + r;
        float e = __expf(acc[ri][cj][r] - lnrm[row]);
        Ebp[(size_t)(r0 + row)*256 + col] = f2bf(e);
        cs += e;
      }
    }
    cs += __shfl_xor(cs, 16); cs += __shfl_xor(cs, 32);
    if (q == 0) atomicAdd(&S[col], cs);
  }
}

__device__ inline void dev_phiA(const float* __restrict__ A,
    const unsigned short* __restrict__ projT, const float* __restrict__ S,
    unsigned short* __restrict__ Eap, int r0,
    float* lnrm, float* sS, float (*wrow)[32], float (*wden)[32])
{
  int tid = threadIdx.x;
  int w = tid >> 6, ln = tid & 63;
  int m16 = ln & 15, q = ln >> 4;
  sS[tid] = S[tid];
  f32x4 acc[2][4];
  zero_acc(acc);
  phi_core(A, projT, r0, C_, w, ln, acc, lnrm);
  __syncthreads();
  int c0 = w*64;
  #pragma unroll
  for (int ri = 0; ri < 2; ++ri){
    #pragma unroll
    for (int r = 0; r < 4; ++r){
      int row = ri*16 + q*4 + r;
      float mv = -1e30f;
      #pragma unroll
      for (int cj = 0; cj < 4; ++cj){
        acc[ri][cj][r] -= lnrm[row];
        mv = fmaxf(mv, acc[ri][cj][r]);
      }
      #pragma unroll
      for (int d = 1; d < 16; d <<= 1) mv = fmaxf(mv, __shfl_xor(mv, d));
      if (m16 == 0) wrow[w][row] = mv;
    }
  }
  __syncthreads();
  float ev[2][4][4];
  float dsum[2][4];
  #pragma unroll
  for (int ri = 0; ri < 2; ++ri){
    #pragma unroll
    for (int r = 0; r < 4; ++r){
      int row = ri*16 + q*4 + r;
      float m = fmaxf(fmaxf(wrow[0][row], wrow[1][row]), fmaxf(wrow[2][row], wrow[3][row]));
      dsum[ri][r] = 0.f;
      #pragma unroll
      for (int cj = 0; cj < 4; ++cj){
        float scol = sS[c0 + cj*16 + m16];
        float e = __expf(acc[ri][cj][r] - m);
        ev[ri][cj][r] = e;
        dsum[ri][r] = fmaf(e, scol, dsum[ri][r]);
      }
      #pragma unroll
      for (int d = 1; d < 16; d <<= 1) dsum[ri][r] += __shfl_xor(dsum[ri][r], d);
      if (m16 == 0) wden[w][row] = dsum[ri][r];
    }
  }
  __syncthreads();
  #pragma unroll
  for (int ri = 0; ri < 2; ++ri){
    #pragma unroll
    for (int r = 0; r < 4; ++r){
      int row = ri*16 + q*4 + r;
      float den = wden[0][row] + wden[1][row] + wden[2][row] + wden[3][row];
      float inv = 1.0f/den;
      #pragma unroll
      for (int cj = 0; cj < 4; ++cj){
        int col = c0 + cj*16 + m16;
        Eap[(size_t)(r0 + row)*256 + col] = f2bf(ev[ri][cj][r]*inv);
      }
    }
  }
}

__device__ inline void phiE_epilogue(f32x4 acc[2][4], unsigned short* __restrict__ E,
    float* __restrict__ mr, int M, int r0, float* lnrm, float (*wrow)[32])
{
  int tid = threadIdx.x;
  int w = tid >> 6, ln = tid & 63;
  int m16 = ln & 15, q = ln >> 4;
  int c0 = w*64;
  #pragma unroll
  for (int ri = 0; ri < 2; ++ri){
    #pragma unroll
    for (int r = 0; r < 4; ++r){
      int row = ri*16 + q*4 + r;
      float mv = -1e30f;
      #pragma unroll
      for (int cj = 0; cj < 4; ++cj){
        acc[ri][cj][r] -= lnrm[row];
        mv = fmaxf(mv, acc[ri][cj][r]);
      }
      #pragma unroll
      for (int d = 1; d < 16; d <<= 1) mv = fmaxf(mv, __shfl_xor(mv, d));
      if (m16 == 0) wrow[w][row] = mv;
    }
  }
  __syncthreads();
  #pragma unroll
  for (int ri = 0; ri < 2; ++ri){
    #pragma unroll
    for (int r = 0; r < 4; ++r){
      int row = ri*16 + q*4 + r;
      int grow = r0 + row;
      float m = fmaxf(fmaxf(wrow[0][row], wrow[1][row]), fmaxf(wrow[2][row], wrow[3][row]));
      if (grow < M){
        #pragma unroll
        for (int cj = 0; cj < 4; ++cj){
          int col = c0 + cj*16 + m16;
          E[(size_t)grow*256 + col] = f2bf(__expf(acc[ri][cj][r] - m));
        }
        if (w == 0 && m16 == 0) mr[grow] = m;
      }
    }
  }
}

__device__ inline void dev_phiE(const float* __restrict__ A,
    const unsigned short* __restrict__ projT, unsigned short* __restrict__ E,
    float* __restrict__ mr, int M, int r0, float* lnrm, float (*wrow)[32])
{
  int tid = threadIdx.x;
  int w = tid >> 6, ln = tid & 63;
  f32x4 acc[2][4];
  zero_acc(acc);
  phi_core(A, projT, r0, M, w, ln, acc, lnrm);
  __syncthreads();
  phiE_epilogue(acc, E, mr, M, r0, lnrm, wrow);
}

// fused 4-layer MLP + phi on slab r0 (sX fp32 / sHb bf16 in LDS)
__device__ inline void dev_mlpAll(const float* __restrict__ pre_emb,
    const unsigned short* __restrict__ WT, const float* __restrict__ term_b,
    const unsigned short* __restrict__ projT,
    unsigned short* __restrict__ Epb, float* __restrict__ mpp, int r0, char* smem)
{
  float* sX = (float*)smem;
  unsigned short* sHb = (unsigned short*)(smem + 32896);
  float* lnrm = (float*)(smem + 49792);
  float (*wrow)[32] = (float(*)[32])(smem + 49920);
  int tid = threadIdx.x;
  int w = tid >> 6, ln = tid & 63;
  int m16 = ln & 15, q = ln >> 4;
  int c0 = w*64;
  f32x4 acc[2][4];
  zero_acc(acc);
  mm_A_gf32(pre_emb, (size_t)r0*256, WT, w, ln, acc);
  #pragma unroll
  for (int ri = 0; ri < 2; ++ri)
    #pragma unroll
    for (int cj = 0; cj < 4; ++cj)
      #pragma unroll
      for (int r = 0; r < 4; ++r){
        int row = ri*16 + q*4 + r, col = c0 + cj*16 + m16;
        sHb[row*HST + col] = f2bf(fmaxf(acc[ri][cj][r] + term_b[col], 0.f));
      }
  __syncthreads();
  zero_acc(acc);
  mm_A_ldsbf(sHb, WT + 65536, w, ln, acc);
  #pragma unroll
  for (int ri = 0; ri < 2; ++ri)
    #pragma unroll
    for (int cj = 0; cj < 4; ++cj)
      #pragma unroll
      for (int r = 0; r < 4; ++r){
        int row = ri*16 + q*4 + r, col = c0 + cj*16 + m16;
        float v = fmaxf(acc[ri][cj][r] + term_b[256 + col], 0.f);
        sX[row*XST + col] = v + pre_emb[(size_t)(r0 + row)*256 + col];
      }
  __syncthreads();
  zero_acc(acc);
  mm_A_ldsf32(sX, WT + 2*65536, w, ln, acc, nullptr);
  __syncthreads();
  #pragma unroll
  for (int ri = 0; ri < 2; ++ri)
    #pragma unroll
    for (int cj = 0; cj < 4; ++cj)
      #pragma unroll
      for (int r = 0; r < 4; ++r){
        int row = ri*16 + q*4 + r, col = c0 + cj*16 + m16;
        sHb[row*HST + col] = f2bf(fmaxf(acc[ri][cj][r] + term_b[512 + col], 0.f));
      }
  __syncthreads();
  zero_acc(acc);
  mm_A_ldsbf(sHb, WT + 3*65536, w, ln, acc);
  #pragma unroll
  for (int ri = 0; ri < 2; ++ri)
    #pragma unroll
    for (int cj = 0; cj < 4; ++cj)
      #pragma unroll
      for (int r = 0; r < 4; ++r){
        int row = ri*16 + q*4 + r, col = c0 + cj*16 + m16;
        sX[row*XST + col] += fmaxf(acc[ri][cj][r] + term_b[768 + col], 0.f);
      }
  __syncthreads();
  zero_acc(acc);
  mm_A_ldsf32(sX, projT, w, ln, acc, lnrm);
  __syncthreads();
  phiE_epilogue(acc, Epb, mpp, C_, r0, lnrm, wrow);
}

// per-cluster emit log-softmax via MFMA
__device__ inline void dev_emit(int k,
    const unsigned short* __restrict__ Epb, const float* __restrict__ mpp,
    const unsigned short* __restrict__ Etb, const float* __restrict__ mt,
    const int* __restrict__ cnt, const int* __restrict__ list,
    float* __restrict__ emit_col, char* smem)
{
  float (*mtile)[32] = (float(*)[32])smem;
  float (*stile)[32] = (float(*)[32])(smem + 1024);
  float* mpl  = (float*)(smem + 2048);
  float* denl = (float*)(smem + 2176);
  int tid = threadIdx.x;
  int w = tid >> 6, ln = tid & 63;
  int m16 = ln & 15, q = ln >> 4;
  if (tid < 32) mpl[tid] = mpp[k*32 + tid];
  int n = cnt[k]; if (n > CAP_) n = CAP_;
  int nt = (n + 31) >> 5;
  const int* lp = list + k*CAP_;
  bf16x8 af0[8], af1[8];
  {
    const unsigned short* ap0 = Epb + (size_t)(k*32 + m16)*256 + q*8;
    const unsigned short* ap1 = ap0 + 16*256;
    #pragma unroll
    for (int kt = 0; kt < 8; ++kt){
      af0[kt] = *(const bf16x8*)(ap0 + kt*32);
      af1[kt] = *(const bf16x8*)(ap1 + kt*32);
    }
  }
  __syncthreads();
  float lg[2][2][2][4];
  int   vj[2][2];
  #pragma unroll
  for (int u = 0; u < 2; ++u){
    int t = w + u*4;
    if (t >= nt) continue;
    int j0 = t*32 + m16, j1 = j0 + 16;
    int v0 = lp[(j0 < n) ? j0 : 0];
    int v1 = lp[(j1 < n) ? j1 : 0];
    vj[u][0] = v0; vj[u][1] = v1;
    float mt0 = (j0 < n) ? mt[v0] : 0.f;
    float mt1 = (j1 < n) ? mt[v1] : 0.f;
    const unsigned short* bp0 = Etb + (size_t)v0*256 + q*8;
    const unsigned short* bp1 = Etb + (size_t)v1*256 + q*8;
    f32x4 acc[2][2];
    #pragma unroll
    for (int mi = 0; mi < 2; ++mi)
      #pragma unroll
      for (int ni = 0; ni < 2; ++ni) acc[mi][ni] = (f32x4){0.f,0.f,0.f,0.f};
    #pragma unroll
    for (int kt = 0; kt < 8; ++kt){
      bf16x8 b0 = *(const bf16x8*)(bp0 + kt*32);
      bf16x8 b1 = *(const bf16x8*)(bp1 + kt*32);
      acc[0][0] = mfma16(af0[kt], b0, acc[0][0]);
      acc[0][1] = mfma16(af0[kt], b1, acc[0][1]);
      acc[1][0] = mfma16(af1[kt], b0, acc[1][0]);
      acc[1][1] = mfma16(af1[kt], b1, acc[1][1]);
    }
    #pragma unroll
    for (int mi = 0; mi < 2; ++mi){
      #pragma unroll
      for (int r = 0; r < 4; ++r){
        int row = mi*16 + q*4 + r;
        float l0 = (j0 < n) ? (__logf(acc[mi][0][r]) + mpl[row] + mt0) : -1e30f;
        float l1 = (j1 < n) ? (__logf(acc[mi][1][r]) + mpl[row] + mt1) : -1e30f;
        lg[u][mi][0][r] = l0;
        lg[u][mi][1][r] = l1;
        float mv = fmaxf(l0, l1);
        #pragma unroll
        for (int d = 1; d < 16; d <<= 1) mv = fmaxf(mv, __shfl_xor(mv, d));
        float se = __expf(l0 - mv) + __expf(l1 - mv);
        #pragma unroll
        for (int d = 1; d < 16; d <<= 1) se += __shfl_xor(se, d);
        if (m16 == 0){ mtile[t][row] = mv; stile[t][row] = se; }
      }
    }
  }
  __syncthreads();
  if (tid < 32){
    float gm = -1e30f;
    for (int t = 0; t < nt; ++t) gm = fmaxf(gm, mtile[t][tid]);
    float gs = 0.f;
    for (int t = 0; t < nt; ++t) gs += stile[t][tid]*__expf(mtile[t][tid] - gm);
    denl[tid] = gm + __logf(gs);
  }
  __syncthreads();
  #pragma unroll
  for (int u = 0; u < 2; ++u){
    int t = w + u*4;
    if (t >= nt) continue;
    #pragma unroll
    for (int ni = 0; ni < 2; ++ni){
      int j = t*32 + ni*16 + m16;
      if (j >= n) continue;
      float* outp = emit_col + (size_t)vj[u][ni]*32;
      #pragma unroll
      for (int mi = 0; mi < 2; ++mi)
        #pragma unroll
        for (int r = 0; r < 4; ++r){
          int row = mi*16 + q*4 + r;
          outp[row] = lg[u][mi][ni][r] - denl[row];
        }
    }
  }
}

// ===========================================================================
// 32x32 product helpers
__device__ inline void prod_acc(const float* __restrict__ L0, const float* __restrict__ L1,
                                f32x4 acc[2][2], int ln)
{
  int m16 = ln & 15, q = ln >> 4;
  bf16x8 af[2], bfv[2];
  #pragma unroll
  for (int mi = 0; mi < 2; ++mi){
    const float* p = L0 + (mi*16 + m16)*MST + q*8;
    u16x8 u;
    #pragma unroll
    for (int jj = 0; jj < 8; ++jj) u[jj] = f2bf(p[jj]);
    af[mi] = __builtin_bit_cast(bf16x8, u);
  }
  #pragma unroll
  for (int ni = 0; ni < 2; ++ni){
    u16x8 u;
    #pragma unroll
    for (int jj = 0; jj < 8; ++jj) u[jj] = f2bf(L1[(q*8 + jj)*MST + ni*16 + m16]);
    bfv[ni] = __builtin_bit_cast(bf16x8, u);
  }
  #pragma unroll
  for (int mi = 0; mi < 2; ++mi)
    #pragma unroll
    for (int ni = 0; ni < 2; ++ni) acc[mi][ni] = mfma16(af[mi], bfv[ni], acc[mi][ni]);
}

__device__ inline void wave_norm_store(f32x4 acc[2][2], float* outp,
                                       float sIn, float* sOut, int ln)
{
  int m16 = ln & 15, q = ln >> 4;
  float mx = 0.f;
  #pragma unroll
  for (int mi = 0; mi < 2; ++mi)
    #pragma unroll
    for (int ni = 0; ni < 2; ++ni)
      #pragma unroll
      for (int r = 0; r < 4; ++r) mx = fmaxf(mx, acc[mi][ni][r]);
  #pragma unroll
  for (int d = 1; d < 64; d <<= 1) mx = fmaxf(mx, __shfl_xor(mx, d));
  float inv = 1.0f/mx;
  #pragma unroll
  for (int mi = 0; mi < 2; ++mi)
    #pragma unroll
    for (int ni = 0; ni < 2; ++ni)
      #pragma unroll
      for (int r = 0; r < 4; ++r)
        outp[(mi*16 + q*4 + r)*MST + ni*16 + m16] = acc[mi][ni][r]*inv;
  if (ln == 0) *sOut = sIn + __logf(mx);
}

__device__ inline void norm_store_g16(f32x4 acc[2][2], unsigned short* outp,
                                      float sIn, float* sOutG, int ln)
{
  int m16 = ln & 15, q = ln >> 4;
  float mx = 0.f;
  #pragma unroll
  for (int mi = 0; mi < 2; ++mi)
    #pragma unroll
    for (int ni = 0; ni < 2; ++ni)
      #pragma unroll
      for (int r = 0; r < 4; ++r) mx = fmaxf(mx, acc[mi][ni][r]);
  #pragma unroll
  for (int d = 1; d < 64; d <<= 1) mx = fmaxf(mx, __shfl_xor(mx, d));
  float inv = 1.0f/mx;
  #pragma unroll
  for (int mi = 0; mi < 2; ++mi)
    #pragma unroll
    for (int ni = 0; ni < 2; ++ni)
      #pragma unroll
      for (int r = 0; r < 4; ++r)
        outp[(mi*16 + q*4 + r)*32 + ni*16 + m16] = f2bf(acc[mi][ni][r]*inv);
  if (ln == 0) *sOutG = sIn + __logf(mx);
}

__device__ inline void prod32(const float* L0, const float* L1, float* outp,
                              float sIn, float* sOut, int ln)
{
  f32x4 acc[2][2];
  #pragma unroll
  for (int mi = 0; mi < 2; ++mi)
    #pragma unroll
    for (int ni = 0; ni < 2; ++ni) acc[mi][ni] = (f32x4){0.f,0.f,0.f,0.f};
  prod_acc(L0, L1, acc, ln);
  wave_norm_store(acc, outp, sIn, sOut, ln);
}

__device__ inline void load_mat16(const unsigned short* __restrict__ g,
                                  float* __restrict__ d, int ln){
  #pragma unroll
  for (int p = 0; p < 16; ++p){
    int idx = p*64 + ln;
    int r = idx >> 5, c = idx & 31;
    d[r*MST + c] = bf2f(g[idx]);
  }
}

// ===========================================================================
// Phase item bodies (shared by mega kernel and standalone fallback kernels)
__device__ inline void phase0_item(int it,
  const float* proj, const float* tw, unsigned short* projT, unsigned short* WT,
  const int* w2s, int* cnt, int* list, const float* se, const float* sw, float* Afx)
{
  int tid = threadIdx.x;
  if (it < 1280){
    int z = it >> 8, dcol = it & 255;
    const float* src = (z == 0) ? proj : (tw + (size_t)(z-1)*65536);
    unsigned short* dst = (z == 0) ? projT : (WT + (size_t)(z-1)*65536);
    dst[dcol*256 + tid] = f2bf(src[tid*256 + dcol]);
  } else if (it < 1320){
    int v = (it - 1280)*256 + tid;
    if (v < V_){
      int k = w2s[v*32] >> 5;
      int pos = atomicAdd(&cnt[k], 1);
      if (pos < CAP_) list[k*CAP_ + pos] = v;
    }
  } else {
    int j = it - 1320;
    float xh[8];
    #pragma unroll
    for (int i = 0; i < 8; ++i) xh[i] = se[8*j + i];
    fx_accum(sw, xh, j, Afx);
  }
}

__device__ inline void phase1_item(int it,
  const float* pre_emb, const unsigned short* WT, const float* term_b,
  const unsigned short* projT, unsigned short* Epb, float* mpp,
  const float* next_emb, unsigned short* Ebp, float* S,
  const float* term_emb, unsigned short* Etb, float* mt,
  const float* sw, const float* sb, float* Afx, char* smem)
{
  if (it < 128){
    dev_mlpAll(pre_emb, WT, term_b, projT, Epb, mpp, it*32, smem);
  } else if (it < 256){
    float* lnrm = (float*)smem;
    dev_phiB(next_emb, projT, Ebp, S, (it - 128)*32, lnrm);
  } else if (it < 569){
    float* lnrm = (float*)smem;
    float (*wrow)[32] = (float(*)[32])(smem + 128);
    dev_phiE(term_emb, projT, Etb, mt, V_, (it - 256)*32, lnrm, wrow);
  } else {
    int j = it - 569;
    float xh[8];
    #pragma unroll
    for (int i = 0; i < 8; ++i){ int h = 8*j + i; xh[i] = Afx[h] + sb[h]; }
    fx_accum(sw + 65536, xh, j, Afx + 256);
  }
}

__device__ inline void phase2_item(int it,
  const float* state_emb, const unsigned short* projT, const float* S,
  unsigned short* Eap, const unsigned short* Epb, const float* mpp,
  const unsigned short* Etb, const float* mt, const int* cnt, const int* list,
  float* emit_col, const float* sw, const float* sb, float* Afx, char* smem)
{
  if (it < 128){
    float* lnrm = (float*)smem;
    float* sS = (float*)(smem + 128);
    float (*wrowA)[32] = (float(*)[32])(smem + 1152);
    float (*wden)[32]  = (float(*)[32])(smem + 1664);
    dev_phiA(state_emb, projT, S, Eap, it*32, lnrm, sS, wrowA, wden);
  } else if (it < 256){
    dev_emit(it - 128, Epb, mpp, Etb, mt, cnt, list, emit_col, smem);
  } else {
    int j = it - 256;
    float xh[8];
    #pragma unroll
    for (int i = 0; i < 8; ++i){ int h = 8*j + i; xh[i] = fmaxf(Afx[256 + h] + sb[256 + h], 0.f); }
    fx_accum(sw + 2*65536, xh, j, Afx + 512);
  }
}

__device__ inline void phase3_item(int it,
  const unsigned short* Eap, const unsigned short* Ebp, const float* emit_col,
  const int* text, const int* w2s, unsigned short* Gm, float* Gs,
  const float* sw, const float* sb, float* Afx, char* smem)
{
  int tid = threadIdx.x;
  if (it >= 512){
    int j = it - 512;
    float xh[8];
    #pragma unroll
    for (int i = 0; i < 8; ++i){
      int h = 8*j + i;
      float x0 = Afx[h] + sb[h];
      xh[i] = x0 + fmaxf(Afx[512 + h] + sb[512 + h], 0.f);
    }
    fx_accum(sw + 3*65536, xh, j, Afx + 768);
    return;
  }
  float* bufL = (float*)smem;
  float* bufN = (float*)(smem + 33792);
  float* sL = (float*)(smem + 50688);
  float* sN = sL + 8;
  float* sT = sN + 4;
  int b = it >> 5, ch = it & 31;
  int w = tid >> 6, ln = tid & 63;
  int m16 = ln & 15, q = ln >> 4;
  #pragma unroll
  for (int u = 0; u < 2; ++u){
    int l = 2*w + u;
    int s = ch*8 + l;
    float* outp = bufL + l*1056;
    if (s >= 255){
      for (int i = ln; i < 32*32; i += 64){
        int r = i >> 5, c = i & 31;
        outp[r*MST + c] = (r == c) ? 1.f : 0.f;
      }
      if (ln == 0) sL[l] = 0.f;
    } else {
      int vp = text[b*256 + s], vc = text[b*256 + s + 1];
      int bp = w2s[vp*32], bq = w2s[vc*32];
      const unsigned short* a0 = Eap + (size_t)(bp + m16)*256 + q*8;
      const unsigned short* b0 = Ebp + (size_t)(bq + m16)*256 + q*8;
      f32x4 acc[2][2];
      #pragma unroll
      for (int mi = 0; mi < 2; ++mi)
        #pragma unroll
        for (int ni = 0; ni < 2; ++ni) acc[mi][ni] = (f32x4){0.f,0.f,0.f,0.f};
      #pragma unroll
      for (int kt = 0; kt < 8; ++kt){
        bf16x8 a_0 = *(const bf16x8*)(a0 + kt*32);
        bf16x8 a_1 = *(const bf16x8*)(a0 + 16*256 + kt*32);
        bf16x8 b_0 = *(const bf16x8*)(b0 + kt*32);
        bf16x8 b_1 = *(const bf16x8*)(b0 + 16*256 + kt*32);
        acc[0][0] = mfma16(a_0, b_0, acc[0][0]);
        acc[0][1] = mfma16(a_0, b_1, acc[0][1]);
        acc[1][0] = mfma16(a_1, b_0, acc[1][0]);
        acc[1][1] = mfma16(a_1, b_1, acc[1][1]);
      }
      float e0 = __expf(emit_col[(size_t)vc*32 + m16]);
      float e1 = __expf(emit_col[(size_t)vc*32 + 16 + m16]);
      #pragma unroll
      for (int mi = 0; mi < 2; ++mi)
        #pragma unroll
        for (int r = 0; r < 4; ++r){
          acc[mi][0][r] *= e0;
          acc[mi][1][r] *= e1;
        }
      wave_norm_store(acc, outp, 0.f, &sL[l], ln);
    }
  }
  prod32(bufL + 2*w*1056, bufL + (2*w+1)*1056, bufN + w*1056,
         sL[2*w] + sL[2*w+1], &sN[w], ln);
  __syncthreads();
  if (w == 0){
    prod32(bufN, bufN + 1056, bufL, sN[0] + sN[1], &sT[0], ln);
    prod32(bufL, bufN + 2*1056, bufL + 1056, sT[0] + sN[2], &sT[1], ln);
    f32x4 acc[2][2];
    #pragma unroll
    for (int mi = 0; mi < 2; ++mi)
      #pragma unroll
      for (int ni = 0; ni < 2; ++ni) acc[mi][ni] = (f32x4){0.f,0.f,0.f,0.f};
    prod_acc(bufL + 1056, bufN + 3*1056, acc, ln);
    norm_store_g16(acc, Gm + (size_t)it*1024, sT[1] + sN[3], Gs + it, ln);
  }
}

__device__ inline void phase4_block(int b,
  const unsigned short* Gm, const float* Gs, const float* Afx, const float* sb,
  const float* sw, const float* proj, const float* S,
  const unsigned short* Ebp, const float* emit_col, const int* text,
  const int* w2s, float* out, char* smem)
{
  float* Wb   = (float*)smem;                     // 4 waves x 3 mats x 1056
  float* sW   = (float*)(smem + 50688);           // 4
  float* sTr  = sW + 4;                           // 1
  float* eafx = (float*)(smem + 50720);           // 256
  float* red  = (float*)(smem + 51744);           // 4
  int tid = threadIdx.x;
  int w = tid >> 6, ln = tid & 63;
  // ---- eafx: fx L4 + proj in-block ----
  {
    float* scr = (float*)smem;                    // alias Wb (pre-tree)
    float* sX2 = scr; float* sH = scr + 256; float* sX4 = scr + 512;
    float x0 = Afx[tid] + sb[tid];
    sX2[tid] = x0 + fmaxf(Afx[512 + tid] + sb[512 + tid], 0.f);
    sH[tid]  = fmaxf(Afx[768 + tid] + sb[768 + tid], 0.f);
    __syncthreads();
    float a0=0.f,a1=0.f,a2=0.f,a3=0.f;
    const float* Wp = sw + 4*65536 + tid;
    #pragma unroll 4
    for (int h = 0; h < 256; h += 4){
      a0 = fmaf(sH[h+0], Wp[(size_t)(h+0)*256], a0);
      a1 = fmaf(sH[h+1], Wp[(size_t)(h+1)*256], a1);
      a2 = fmaf(sH[h+2], Wp[(size_t)(h+2)*256], a2);
      a3 = fmaf(sH[h+3], Wp[(size_t)(h+3)*256], a3);
    }
    float A4 = (a0+a1)+(a2+a3);
    float x4 = sX2[tid] + fmaxf(A4 + sb[1024 + tid], 0.f);
    sX4[tid] = x4;
    float v2 = x4*x4;
    #pragma unroll
    for (int d = 1; d < 64; d <<= 1) v2 += __shfl_xor(v2, d);
    if ((tid & 63) == 0) red[tid >> 6] = v2;
    __syncthreads();
    float nx = red[0]+red[1]+red[2]+red[3];
    a0=a1=a2=a3=0.f;
    const float* Pp = proj + tid;
    #pragma unroll 4
    for (int h = 0; h < 256; h += 4){
      a0 = fmaf(sX4[h+0], Pp[(size_t)(h+0)*256], a0);
      a1 = fmaf(sX4[h+1], Pp[(size_t)(h+1)*256], a1);
      a2 = fmaf(sX4[h+2], Pp[(size_t)(h+2)*256], a2);
      a3 = fmaf(sX4[h+3], Pp[(size_t)(h+3)*256], a3);
    }
    float pxv = (a0+a1)+(a2+a3) - 0.5f*nx;
    __syncthreads();
    float m2 = pxv;
    #pragma unroll
    for (int d = 1; d < 64; d <<= 1) m2 = fmaxf(m2, __shfl_xor(m2, d));
    if ((tid & 63) == 0) red[tid >> 6] = m2;
    __syncthreads();
    float m2g = fmaxf(fmaxf(red[0], red[1]), fmaxf(red[2], red[3]));
    eafx[tid] = __expf(pxv - m2g);
    __syncthreads();
  }
  // ---- chunk-matrix tree: wave w reduces mats [8w, 8w+8) ----
  {
    const unsigned short* G = Gm + ((size_t)(b*32 + w*8))*1024;
    const float* gs = Gs + b*32 + w*8;
    float* W0 = Wb + (w*3 + 0)*1056;
    float* W1 = Wb + (w*3 + 1)*1056;
    float* W2 = Wb + (w*3 + 2)*1056;
    load_mat16(G,        W0, ln);
    load_mat16(G + 1024, W1, ln);
    prod32(W0, W1, W2, gs[0] + gs[1], &sW[w], ln);
    int cur = 2;
    for (int j = 2; j < 8; ++j){
      load_mat16(G + (size_t)j*1024, W0, ln);
      int dst = (cur == 2) ? 1 : 2;
      float* curp = (cur == 2) ? W2 : W1;
      float* dstp = (dst == 2) ? W2 : W1;
      prod32(curp, W0, dstp, sW[w] + gs[j], &sW[w], ln);
      cur = dst;
    }
  }
  __syncthreads();
  if (w == 0){
    float* N0 = Wb + 2*1056;
    float* N1 = Wb + (1*3 + 2)*1056;
    float* N2 = Wb + (2*3 + 2)*1056;
    float* N3 = Wb + (3*3 + 2)*1056;
    float* T0 = Wb;
    float* T1 = Wb + 1056;
    prod32(N0, N1, T0, sW[0] + sW[1], &sTr[0], ln);
    prod32(T0, N2, T1, sTr[0] + sW[2], &sTr[0], ln);
    prod32(T1, N3, T0, sTr[0] + sW[3], &sTr[0], ln);
    float sAcc = sTr[0];
    const float* cur = T0;
    float part = 0.f;
    for (int d = ln; d < 256; d += 64) part = fmaf(eafx[d], S[d], part);
    #pragma unroll
    for (int d2 = 1; d2 < 64; d2 <<= 1) part += __shfl_xor(part, d2);
    float dfx = part;
    int v0 = text[b*256];
    int k0 = w2s[v0*32];
    int j = ln & 31, h = ln >> 5;
    const unsigned short* er = Ebp + (size_t)(k0 + j)*256;
    float dot = 0.f;
    for (int d = h*128; d < h*128 + 128; ++d)
      dot = fmaf(eafx[d], bf2f(er[d]), dot);
    dot += __shfl_xor(dot, 32);
    float z0 = __logf(dot) + emit_col[(size_t)v0*32 + j];
    float mz = z0;
    #pragma unroll
    for (int d2 = 1; d2 < 32; d2 <<= 1) mz = fmaxf(mz, __shfl_xor(mz, d2));
    float an = __expf(z0 - mz);
    float cs = 0.f;
    for (int i = h*16; i < h*16 + 16; ++i)
      cs = fmaf(__shfl(an, i), cur[i*MST + j], cs);
    cs += __shfl_xor(cs, 32);
    float tot = cs;
    #pragma unroll
    for (int d2 = 1; d2 < 32; d2 <<= 1) tot += __shfl_xor(tot, d2);
    if (ln == 0) out[b] = __logf(tot) + mz + sAcc - __logf(dfx);
  }
}

// ===========================================================================
// Mega cooperative kernel: 5 phases, grid.sync between phases. 256 blocks.
__global__ __launch_bounds__(256) void k_mega(
  const float* proj, const float* tw, unsigned short* projT, unsigned short* WT,
  const int* w2s, int* cnt, int* list, const float* se, const float* sw,
  const float* sb, float* Afx, const float* pre_emb, const float* term_b,
  unsigned short* Epb, float* mpp, const float* next_emb, unsigned short* Ebp,
  float* S, const float* term_emb, unsigned short* Etb, float* mt,
  const float* state_emb, unsigned short* Eap, float* emit_col,
  const int* text, unsigned short* Gm, float* Gs, float* out)
{
  __shared__ __align__(16) char smem[SMEM_BYTES];
  cg::grid_group grid = cg::this_grid();
  int nb = gridDim.x;
  for (int it = blockIdx.x; it < 1352; it += nb)
    phase0_item(it, proj, tw, projT, WT, w2s, cnt, list, se, sw, Afx);
  grid.sync();
  for (int it = blockIdx.x; it < 601; it += nb){
    __syncthreads();
    phase1_item(it, pre_emb, WT, term_b, projT, Epb, mpp, next_emb, Ebp, S,
                term_emb, Etb, mt, sw, sb, Afx, smem);
  }
  grid.sync();
  for (int it = blockIdx.x; it < 288; it += nb){
    __syncthreads();
    phase2_item(it, state_emb, projT, S, Eap, Epb, mpp, Etb, mt, cnt, list,
                emit_col, sw, sb, Afx, smem);
  }
  grid.sync();
  for (int it = blockIdx.x; it < 544; it += nb){
    __syncthreads();
    phase3_item(it, Eap, Ebp, emit_col, text, w2s, Gm, Gs, sw, sb, Afx, smem);
  }
  grid.sync();
  if (blockIdx.x < B_)
    phase4_block(blockIdx.x, Gm, Gs, Afx, sb, sw, proj, S, Ebp, emit_col,
                 text, w2s, out, smem);
}

// ===========================================================================
// Standalone fallback kernels (identical phase bodies)
__global__ __launch_bounds__(256) void k_p0(
  const float* proj, const float* tw, unsigned short* projT, unsigned short* WT,
  const int* w2s, int* cnt, int* list, const float* se, const float* sw, float* Afx)
{
  phase0_item(blockIdx.x, proj, tw, projT, WT, w2s, cnt, list, se, sw, Afx);
}

__global__ __launch_bounds__(256) void k_p1(
  const float* pre_emb, const unsigned short* WT, const float* term_b,
  const unsigned short* projT, unsigned short* Epb, float* mpp,
  const float* next_emb, unsigned short* Ebp, float* S,
  const float* term_emb, unsigned short* Etb, float* mt,
  const float* sw, const float* sb, float* Afx)
{
  __shared__ __align__(16) char smem[SMEM_BYTES];
  phase1_item(blockIdx.x, pre_emb, WT, term_b, projT, Epb, mpp, next_emb, Ebp,
              S, term_emb, Etb, mt, sw, sb, Afx, smem);
}

__global__ __launch_bounds__(256) void k_p2(
  const float* state_emb, const unsigned short* projT, const float* S,
  unsigned short* Eap, const unsigned short* Epb, const float* mpp,
  const unsigned short* Etb, const float* mt, const int* cnt, const int* list,
  float* emit_col, const float* sw, const float* sb, float* Afx)
{
  __shared__ __align__(16) char smem[4096];
  phase2_item(blockIdx.x, state_emb, projT, S, Eap, Epb, mpp, Etb, mt, cnt,
              list, emit_col, sw, sb, Afx, smem);
}

__global__ __launch_bounds__(256) void k_p3(
  const unsigned short* Eap, const unsigned short* Ebp, const float* emit_col,
  const int* text, const int* w2s, unsigned short* Gm, float* Gs,
  const float* sw, const float* sb, float* Afx)
{
  __shared__ __align__(16) char smem[SMEM_BYTES];
  phase3_item(blockIdx.x, Eap, Ebp, emit_col, text, w2s, Gm, Gs, sw, sb, Afx, smem);
}

__global__ __launch_bounds__(256) void k_p4(
  const unsigned short* Gm, const float* Gs, const float* Afx, const float* sb,
  const float* sw, const float* proj, const float* S,
  const unsigned short* Ebp, const float* emit_col, const int* text,
  const int* w2s, float* out)
{
  __shared__ __align__(16) char smem[SMEM_BYTES];
  phase4_block(blockIdx.x, Gm, Gs, Afx, sb, sw, proj, S, Ebp, emit_col,
               text, w2s, out, smem);
}

// ===========================================================================
extern "C" void kernel_launch(void* const* d_in, const int* in_sizes, int n_in,
                              void* d_out, int out_size, void* d_ws, size_t ws_size,
                              hipStream_t stream)
{
  (void)in_sizes; (void)n_in; (void)out_size; (void)ws_size;
  const int*   text      = (const int*)  d_in[0];
  const float* start_emb = (const float*)d_in[1];
  const float* start_w   = (const float*)d_in[2];
  const float* start_b   = (const float*)d_in[3];
  const float* state_emb = (const float*)d_in[4];
  const float* next_emb  = (const float*)d_in[5];
  const float* pre_emb   = (const float*)d_in[6];
  const float* term_w    = (const float*)d_in[7];
  const float* term_b    = (const float*)d_in[8];
  const float* term_emb  = (const float*)d_in[9];
  const float* proj      = (const float*)d_in[10];
  const int*   w2s       = (const int*)  d_in[11];
  float* out = (float*)d_out;

  char* base = (char*)d_ws;
  size_t off = 0;
  auto alloc = [&](size_t bytes)->char*{
    char* p = base + off;
    off += (bytes + 255) & ~(size_t)255;
    return p;
  };
  int*   cnt = (int*)  alloc(128*4);
  float* Afx = (float*)alloc(4*256*4);
  float* S   = (float*)alloc(256*4);
  unsigned short* projT = (unsigned short*)alloc((size_t)65536*2);
  unsigned short* WT    = (unsigned short*)alloc((size_t)4*65536*2);
  unsigned short* Epb = (unsigned short*)alloc((size_t)C_*256*2);
  float* mpp  = (float*)alloc((size_t)C_*4);
  unsigned short* Etb = (unsigned short*)alloc((size_t)V_*256*2);
  float* mt   = (float*)alloc((size_t)V_*4);
  unsigned short* Eap = (unsigned short*)alloc((size_t)C_*256*2);
  unsigned short* Ebp = (unsigned short*)alloc((size_t)C_*256*2);
  int* list = (int*)alloc((size_t)128*CAP_*4);
  float* emit_col = (float*)alloc((size_t)V_*32*4);
  unsigned short* Gm = (unsigned short*)alloc((size_t)512*1024*2);
  float* Gs = (float*)alloc((size_t)512*4);

  (void)hipMemsetAsync(cnt, 0, 512 + 4096 + 1024, stream);

  void* kargs[] = {
    (void*)&proj, (void*)&term_w, (void*)&projT, (void*)&WT, (void*)&w2s,
    (void*)&cnt, (void*)&list, (void*)&start_emb, (void*)&start_w,
    (void*)&start_b, (void*)&Afx, (void*)&pre_emb, (void*)&term_b,
    (void*)&Epb, (void*)&mpp, (void*)&next_emb, (void*)&Ebp, (void*)&S,
    (void*)&term_emb, (void*)&Etb, (void*)&mt, (void*)&state_emb,
    (void*)&Eap, (void*)&emit_col, (void*)&text, (void*)&Gm, (void*)&Gs,
    (void*)&out
  };
  hipError_t err = hipLaunchCooperativeKernel((void*)k_mega, dim3(256),
                                              dim3(256), kargs, 0, stream);
  if (err != hipSuccess){
    (void)hipGetLastError();   // clear sticky error
    k_p0<<<1352, 256, 0, stream>>>(proj, term_w, projT, WT, w2s, cnt, list,
                                   start_emb, start_w, Afx);
    k_p1<<<601, 256, 0, stream>>>(pre_emb, WT, term_b, projT, Epb, mpp,
                                  next_emb, Ebp, S, term_emb, Etb, mt,
                                  start_w, start_b, Afx);
    k_p2<<<288, 256, 0, stream>>>(state_emb, projT, S, Eap, Epb, mpp, Etb, mt,
                                  cnt, list, emit_col, start_w, start_b, Afx);
    k_p3<<<544, 256, 0, stream>>>(Eap, Ebp, emit_col, text, w2s, Gm, Gs,
                                  start_w, start_b, Afx);
    k_p4<<<16, 256, 0, stream>>>(Gm, Gs, Afx, start_b, start_w, proj, S,
                                 Ebp, emit_col, text, w2s, out);
  }
}

// Round 11
// 198.945 us; speedup vs baseline: 2.2024x; 2.2024x over previous
//
#include <hip/hip_runtime.h>

#define B_   16
#define T_   256
#define V_   10000
#define C_   4096
#define NC_  128
#define CAP_ 224
#define MST  33    // LDS fp32 matrix stride (32+1)
#define XST  257   // LDS fp32 slab stride
#define HST  264   // LDS bf16 slab stride (16B-aligned rows)

typedef __bf16 bf16x8 __attribute__((ext_vector_type(8)));
typedef unsigned short u16x8 __attribute__((ext_vector_type(8)));
typedef float  f32x4  __attribute__((ext_vector_type(4)));

__device__ inline unsigned short f2bf(float f){
  unsigned int u = __float_as_uint(f);
  u += 0x7FFFu + ((u >> 16) & 1u);
  return (unsigned short)(u >> 16);
}
__device__ inline float bf2f(unsigned short u){
  return __uint_as_float(((unsigned int)u) << 16);
}
__device__ inline f32x4 mfma16(bf16x8 a, bf16x8 b, f32x4 c){
  return __builtin_amdgcn_mfma_f32_16x16x32_bf16(a, b, c, 0, 0, 0);
}
__device__ inline bf16x8 load_cvt8(const float* p){
  u16x8 u;
  #pragma unroll
  for (int i = 0; i < 8; ++i) u[i] = f2bf(p[i]);
  return __builtin_bit_cast(bf16x8, u);
}
__device__ inline void zero_acc(f32x4 acc[2][4]){
  #pragma unroll
  for (int i = 0; i < 2; ++i)
    #pragma unroll
    for (int jx = 0; jx < 4; ++jx) acc[i][jx] = (f32x4){0.f,0.f,0.f,0.f};
}

// fx accumulators in Afx: A0,A1,A2,A3 (4 x 256 floats)
__device__ inline void fx_accum(const float* __restrict__ W, const float* xh,
                                int j, float* __restrict__ Anext){
  int t = threadIdx.x;
  float p = 0.f;
  #pragma unroll
  for (int i = 0; i < 8; ++i)
    p = fmaf(xh[i], W[(size_t)(8*j + i)*256 + t], p);
  atomicAdd(&Anext[t], p);
}

// ===========================================================================
// GEMM cores (32-row slab x 256 cols)
__device__ inline void mm_A_gf32(const float* __restrict__ A, size_t lda_row0,
    const unsigned short* __restrict__ Bt, int w, int ln, f32x4 acc[2][4]){
  int m16 = ln & 15, q = ln >> 4, c0 = w*64;
  const float* a0 = A + lda_row0 + (size_t)m16*256 + q*8;
  const float* a1 = a0 + 16*256;
  const unsigned short* bp0 = Bt + (size_t)(c0 + m16)*256 + q*8;
  #pragma unroll
  for (int kt = 0; kt < 8; ++kt){
    bf16x8 af0 = load_cvt8(a0 + kt*32);
    bf16x8 af1 = load_cvt8(a1 + kt*32);
    #pragma unroll
    for (int cj = 0; cj < 4; ++cj){
      bf16x8 bfj = *(const bf16x8*)(bp0 + (size_t)cj*16*256 + kt*32);
      acc[0][cj] = mfma16(af0, bfj, acc[0][cj]);
      acc[1][cj] = mfma16(af1, bfj, acc[1][cj]);
    }
  }
}

__device__ inline void mm_A_ldsbf(const unsigned short* sHb,
    const unsigned short* __restrict__ Bt, int w, int ln, f32x4 acc[2][4]){
  int m16 = ln & 15, q = ln >> 4, c0 = w*64;
  const unsigned short* a0 = sHb + m16*HST + q*8;
  const unsigned short* a1 = sHb + (16 + m16)*HST + q*8;
  const unsigned short* bp0 = Bt + (size_t)(c0 + m16)*256 + q*8;
  #pragma unroll
  for (int kt = 0; kt < 8; ++kt){
    bf16x8 af0 = *(const bf16x8*)(a0 + kt*32);
    bf16x8 af1 = *(const bf16x8*)(a1 + kt*32);
    #pragma unroll
    for (int cj = 0; cj < 4; ++cj){
      bf16x8 bfj = *(const bf16x8*)(bp0 + (size_t)cj*16*256 + kt*32);
      acc[0][cj] = mfma16(af0, bfj, acc[0][cj]);
      acc[1][cj] = mfma16(af1, bfj, acc[1][cj]);
    }
  }
}

__device__ inline void mm_A_ldsf32(const float* sX,
    const unsigned short* __restrict__ Bt, int w, int ln, f32x4 acc[2][4],
    float* lnrm){
  int m16 = ln & 15, q = ln >> 4, c0 = w*64;
  const float* a0 = sX + m16*XST + q*8;
  const float* a1 = sX + (16 + m16)*XST + q*8;
  const unsigned short* bp0 = Bt + (size_t)(c0 + m16)*256 + q*8;
  float ss0 = 0.f, ss1 = 0.f;
  #pragma unroll
  for (int kt = 0; kt < 8; ++kt){
    float av0[8], av1[8];
    #pragma unroll
    for (int i2 = 0; i2 < 8; ++i2){ av0[i2] = a0[kt*32 + i2]; av1[i2] = a1[kt*32 + i2]; }
    u16x8 u0, u1;
    #pragma unroll
    for (int i2 = 0; i2 < 8; ++i2){
      u0[i2] = f2bf(av0[i2]); u1[i2] = f2bf(av1[i2]);
      ss0 = fmaf(av0[i2], av0[i2], ss0);
      ss1 = fmaf(av1[i2], av1[i2], ss1);
    }
    bf16x8 af0 = __builtin_bit_cast(bf16x8, u0);
    bf16x8 af1 = __builtin_bit_cast(bf16x8, u1);
    #pragma unroll
    for (int cj = 0; cj < 4; ++cj){
      bf16x8 bfj = *(const bf16x8*)(bp0 + (size_t)cj*16*256 + kt*32);
      acc[0][cj] = mfma16(af0, bfj, acc[0][cj]);
      acc[1][cj] = mfma16(af1, bfj, acc[1][cj]);
    }
  }
  if (lnrm){
    ss0 += __shfl_xor(ss0, 16); ss0 += __shfl_xor(ss0, 32);
    ss1 += __shfl_xor(ss1, 16); ss1 += __shfl_xor(ss1, 32);
    if (w == 0 && q == 0){ lnrm[m16] = 0.5f*ss0; lnrm[16 + m16] = 0.5f*ss1; }
  }
}

// phi core from GLOBAL fp32 A (row-clamped), with norm
__device__ inline void phi_core(const float* __restrict__ A,
    const unsigned short* __restrict__ Bt, int r0, int M, int w, int ln,
    f32x4 acc[2][4], float* lnrm)
{
  int m16 = ln & 15, q = ln >> 4;
  int c0 = w*64;
  int ra0 = r0 + m16;      if (ra0 > M-1) ra0 = M-1;
  int ra1 = r0 + 16 + m16; if (ra1 > M-1) ra1 = M-1;
  const float* a0 = A + (size_t)ra0*256 + q*8;
  const float* a1 = A + (size_t)ra1*256 + q*8;
  const unsigned short* bp0 = Bt + (size_t)(c0 + m16)*256 + q*8;
  float ss0 = 0.f, ss1 = 0.f;
  #pragma unroll
  for (int kt = 0; kt < 8; ++kt){
    float av0[8], av1[8];
    #pragma unroll
    for (int i2 = 0; i2 < 8; ++i2){ av0[i2] = a0[kt*32 + i2]; av1[i2] = a1[kt*32 + i2]; }
    u16x8 u0, u1;
    #pragma unroll
    for (int i2 = 0; i2 < 8; ++i2){
      u0[i2] = f2bf(av0[i2]); u1[i2] = f2bf(av1[i2]);
      ss0 = fmaf(av0[i2], av0[i2], ss0);
      ss1 = fmaf(av1[i2], av1[i2], ss1);
    }
    bf16x8 af0 = __builtin_bit_cast(bf16x8, u0);
    bf16x8 af1 = __builtin_bit_cast(bf16x8, u1);
    #pragma unroll
    for (int cj = 0; cj < 4; ++cj){
      bf16x8 bfj = *(const bf16x8*)(bp0 + (size_t)cj*16*256 + kt*32);
      acc[0][cj] = mfma16(af0, bfj, acc[0][cj]);
      acc[1][cj] = mfma16(af1, bfj, acc[1][cj]);
    }
  }
  ss0 += __shfl_xor(ss0, 16); ss0 += __shfl_xor(ss0, 32);
  ss1 += __shfl_xor(ss1, 16); ss1 += __shfl_xor(ss1, 32);
  if (w == 0 && q == 0){ lnrm[m16] = 0.5f*ss0; lnrm[16 + m16] = 0.5f*ss1; }
}

// ===========================================================================
// phiB: Ebp = bf16(exp(phi)), S += colsums (atomic)
__device__ inline void dev_phiB(const float* __restrict__ A,
    const unsigned short* __restrict__ projT, unsigned short* __restrict__ Ebp,
    float* __restrict__ S, int r0, float* lnrm)
{
  int tid = threadIdx.x;
  int w = tid >> 6, ln = tid & 63;
  int m16 = ln & 15, q = ln >> 4;
  f32x4 acc[2][4];
  zero_acc(acc);
  phi_core(A, projT, r0, C_, w, ln, acc, lnrm);
  __syncthreads();
  int c0 = w*64;
  #pragma unroll
  for (int cj = 0; cj < 4; ++cj){
    int col = c0 + cj*16 + m16;
    float cs = 0.f;
    #pragma unroll
    for (int ri = 0; ri < 2; ++ri){
      #pragma unroll
      for (int r = 0; r < 4; ++r){
        int row = ri*16 + q*4 + r;
        float e = __expf(acc[ri][cj][r] - lnrm[row]);
        Ebp[(size_t)(r0 + row)*256 + col] = f2bf(e);
        cs += e;
      }
    }
    cs += __shfl_xor(cs, 16); cs += __shfl_xor(cs, 32);
    if (q == 0) atomicAdd(&S[col], cs);
  }
}

// ===========================================================================
// phiE epilogue from acc: E = bf16(exp(phi - rowmax)), mr = rowmax
__device__ inline void phiE_epilogue(f32x4 acc[2][4], unsigned short* __restrict__ E,
    float* __restrict__ mr, int M, int r0, float* lnrm, float (*wrow)[32])
{
  int tid = threadIdx.x;
  int w = tid >> 6, ln = tid & 63;
  int m16 = ln & 15, q = ln >> 4;
  int c0 = w*64;
  #pragma unroll
  for (int ri = 0; ri < 2; ++ri){
    #pragma unroll
    for (int r = 0; r < 4; ++r){
      int row = ri*16 + q*4 + r;
      float mv = -1e30f;
      #pragma unroll
      for (int cj = 0; cj < 4; ++cj){
        acc[ri][cj][r] -= lnrm[row];
        mv = fmaxf(mv, acc[ri][cj][r]);
      }
      #pragma unroll
      for (int d = 1; d < 16; d <<= 1) mv = fmaxf(mv, __shfl_xor(mv, d));
      if (m16 == 0) wrow[w][row] = mv;
    }
  }
  __syncthreads();
  #pragma unroll
  for (int ri = 0; ri < 2; ++ri){
    #pragma unroll
    for (int r = 0; r < 4; ++r){
      int row = ri*16 + q*4 + r;
      int grow = r0 + row;
      float m = fmaxf(fmaxf(wrow[0][row], wrow[1][row]), fmaxf(wrow[2][row], wrow[3][row]));
      if (grow < M){
        #pragma unroll
        for (int cj = 0; cj < 4; ++cj){
          int col = c0 + cj*16 + m16;
          E[(size_t)grow*256 + col] = f2bf(__expf(acc[ri][cj][r] - m));
        }
        if (w == 0 && m16 == 0) mr[grow] = m;
      }
    }
  }
}

__device__ inline void dev_phiE(const float* __restrict__ A,
    const unsigned short* __restrict__ projT, unsigned short* __restrict__ E,
    float* __restrict__ mr, int M, int r0, float* lnrm, float (*wrow)[32])
{
  int tid = threadIdx.x;
  int w = tid >> 6, ln = tid & 63;
  f32x4 acc[2][4];
  zero_acc(acc);
  phi_core(A, projT, r0, M, w, ln, acc, lnrm);
  __syncthreads();
  phiE_epilogue(acc, E, mr, M, r0, lnrm, wrow);
}

// ===========================================================================
// k_prep: tpack (0..1279) | lists (1280..1319) | fx L0 (1320..1351)
__global__ __launch_bounds__(256) void k_prep(
  const float* __restrict__ proj, const float* __restrict__ tw,
  unsigned short* __restrict__ projT, unsigned short* __restrict__ WT,
  const int* __restrict__ w2s, int* __restrict__ cnt, int* __restrict__ list,
  const float* __restrict__ se, const float* __restrict__ sw,
  float* __restrict__ Afx)
{
  int bx = blockIdx.x, tid = threadIdx.x;
  if (bx < 1280){
    int z = bx >> 8, dcol = bx & 255;
    const float* src = (z == 0) ? proj : (tw + (size_t)(z-1)*65536);
    unsigned short* dst = (z == 0) ? projT : (WT + (size_t)(z-1)*65536);
    dst[dcol*256 + tid] = f2bf(src[tid*256 + dcol]);
    return;
  }
  if (bx < 1320){
    int v = (bx - 1280)*256 + tid;
    if (v < V_){
      int k = w2s[v*32] >> 5;
      int pos = atomicAdd(&cnt[k], 1);
      if (pos < CAP_) list[k*CAP_ + pos] = v;
    }
    return;
  }
  int j = bx - 1320;
  float xh[8];
  #pragma unroll
  for (int i = 0; i < 8; ++i) xh[i] = se[8*j + i];
  fx_accum(sw, xh, j, Afx);
}

// ===========================================================================
// k_stageB: mlpAll (0..127) | phiB (128..255) | phiE-term (256..568)
//           | fxL1 (569..600) | phiE-state (601..728)
__global__ __launch_bounds__(256) void k_stageB(
  const float* __restrict__ pre_emb, const unsigned short* __restrict__ WT,
  const float* __restrict__ term_b,
  const unsigned short* __restrict__ projT,
  unsigned short* __restrict__ Epb, float* __restrict__ mpp,
  const float* __restrict__ next_emb, unsigned short* __restrict__ Ebp,
  float* __restrict__ S,
  const float* __restrict__ term_emb, unsigned short* __restrict__ Etb,
  float* __restrict__ mt,
  const float* __restrict__ sw, const float* __restrict__ sb,
  float* __restrict__ Afx,
  const float* __restrict__ state_emb, unsigned short* __restrict__ Eab,
  float* __restrict__ maS)
{
  __shared__ __align__(16) float sX[32*XST];
  __shared__ __align__(16) unsigned short sHb[32*HST];
  __shared__ float lnrm[32];
  __shared__ float wrow[4][32];
  int bx = blockIdx.x, tid = threadIdx.x;
  int w = tid >> 6, ln = tid & 63;
  int m16 = ln & 15, q = ln >> 4;
  int c0 = w*64;
  if (bx < 128){
    // ---- fused 4-layer MLP + phi on slab r0 ----
    int r0 = bx*32;
    f32x4 acc[2][4];
    zero_acc(acc);
    mm_A_gf32(pre_emb, (size_t)r0*256, WT, w, ln, acc);
    #pragma unroll
    for (int ri = 0; ri < 2; ++ri)
      #pragma unroll
      for (int cj = 0; cj < 4; ++cj)
        #pragma unroll
        for (int r = 0; r < 4; ++r){
          int row = ri*16 + q*4 + r, col = c0 + cj*16 + m16;
          sHb[row*HST + col] = f2bf(fmaxf(acc[ri][cj][r] + term_b[col], 0.f));
        }
    __syncthreads();
    zero_acc(acc);
    mm_A_ldsbf(sHb, WT + 65536, w, ln, acc);
    #pragma unroll
    for (int ri = 0; ri < 2; ++ri)
      #pragma unroll
      for (int cj = 0; cj < 4; ++cj)
        #pragma unroll
        for (int r = 0; r < 4; ++r){
          int row = ri*16 + q*4 + r, col = c0 + cj*16 + m16;
          float v = fmaxf(acc[ri][cj][r] + term_b[256 + col], 0.f);
          sX[row*XST + col] = v + pre_emb[(size_t)(r0 + row)*256 + col];
        }
    __syncthreads();
    zero_acc(acc);
    mm_A_ldsf32(sX, WT + 2*65536, w, ln, acc, nullptr);
    __syncthreads();
    #pragma unroll
    for (int ri = 0; ri < 2; ++ri)
      #pragma unroll
      for (int cj = 0; cj < 4; ++cj)
        #pragma unroll
        for (int r = 0; r < 4; ++r){
          int row = ri*16 + q*4 + r, col = c0 + cj*16 + m16;
          sHb[row*HST + col] = f2bf(fmaxf(acc[ri][cj][r] + term_b[512 + col], 0.f));
        }
    __syncthreads();
    zero_acc(acc);
    mm_A_ldsbf(sHb, WT + 3*65536, w, ln, acc);
    #pragma unroll
    for (int ri = 0; ri < 2; ++ri)
      #pragma unroll
      for (int cj = 0; cj < 4; ++cj)
        #pragma unroll
        for (int r = 0; r < 4; ++r){
          int row = ri*16 + q*4 + r, col = c0 + cj*16 + m16;
          sX[row*XST + col] += fmaxf(acc[ri][cj][r] + term_b[768 + col], 0.f);
        }
    __syncthreads();
    zero_acc(acc);
    mm_A_ldsf32(sX, projT, w, ln, acc, lnrm);
    __syncthreads();
    phiE_epilogue(acc, Epb, mpp, C_, r0, lnrm, wrow);
  } else if (bx < 256){
    dev_phiB(next_emb, projT, Ebp, S, (bx - 128)*32, lnrm);
  } else if (bx < 569){
    dev_phiE(term_emb, projT, Etb, mt, V_, (bx - 256)*32, lnrm, wrow);
  } else if (bx < 601){
    int j = bx - 569;
    float xh[8];
    #pragma unroll
    for (int i = 0; i < 8; ++i){ int h = 8*j + i; xh[i] = Afx[h] + sb[h]; }
    fx_accum(sw + 65536, xh, j, Afx + 256);
  } else {
    // phi(state_emb) raw: Eab = bf16(exp(phi - rowmax))
    dev_phiE(state_emb, projT, Eab, maS, C_, (bx - 601)*32, lnrm, wrow);
  }
}

// ===========================================================================
// k_stageC: emit (0..127) | denInv (128..191) | fx L2 (192..223)
__global__ __launch_bounds__(256) void k_stageC(
  const unsigned short* __restrict__ Epb, const float* __restrict__ mpp,
  const unsigned short* __restrict__ Etb, const float* __restrict__ mt,
  const int* __restrict__ cnt, const int* __restrict__ list,
  float* __restrict__ emit_col,
  const unsigned short* __restrict__ Eab, const float* __restrict__ S,
  float* __restrict__ denInv,
  const float* __restrict__ sw, const float* __restrict__ sb,
  float* __restrict__ Afx)
{
  __shared__ float mtile[8][32];
  __shared__ float stile[8][32];
  __shared__ float mpl[32];
  __shared__ float denl[32];
  int bx = blockIdx.x, tid = threadIdx.x;
  if (bx >= 192){
    // fx L2: A2 = h1 @ W2, h1 = relu(A1 + b1)
    int j = bx - 192;
    float xh[8];
    #pragma unroll
    for (int i = 0; i < 8; ++i){ int h = 8*j + i; xh[i] = fmaxf(Afx[256 + h] + sb[256 + h], 0.f); }
    fx_accum(sw + 2*65536, xh, j, Afx + 512);
    return;
  }
  if (bx >= 128){
    // denInv[c] = 1 / dot(Eab[c], S), 64 rows per block, 4 threads/row
    int g = bx - 128;
    int r = g*64 + (tid >> 2);
    int seg = tid & 3;
    const unsigned short* er = Eab + (size_t)r*256 + seg*64;
    const float* sp = S + seg*64;
    float s = 0.f;
    #pragma unroll 8
    for (int i = 0; i < 64; ++i) s = fmaf(bf2f(er[i]), sp[i], s);
    s += __shfl_xor(s, 1);
    s += __shfl_xor(s, 2);
    if (seg == 0) denInv[r] = 1.0f / s;
    return;
  }
  // ---- emit arm ----
  int k = bx;
  int w = tid >> 6, ln = tid & 63;
  int m16 = ln & 15, q = ln >> 4;
  if (tid < 32) mpl[tid] = mpp[k*32 + tid];
  int n = cnt[k]; if (n > CAP_) n = CAP_;
  int nt = (n + 31) >> 5;
  const int* lp = list + k*CAP_;
  bf16x8 af0[8], af1[8];
  {
    const unsigned short* ap0 = Epb + (size_t)(k*32 + m16)*256 + q*8;
    const unsigned short* ap1 = ap0 + 16*256;
    #pragma unroll
    for (int kt = 0; kt < 8; ++kt){
      af0[kt] = *(const bf16x8*)(ap0 + kt*32);
      af1[kt] = *(const bf16x8*)(ap1 + kt*32);
    }
  }
  __syncthreads();
  float lg[2][2][2][4];
  int   vj[2][2];
  #pragma unroll
  for (int u = 0; u < 2; ++u){
    int t = w + u*4;
    if (t >= nt) continue;
    int j0 = t*32 + m16, j1 = j0 + 16;
    int v0 = lp[(j0 < n) ? j0 : 0];
    int v1 = lp[(j1 < n) ? j1 : 0];
    vj[u][0] = v0; vj[u][1] = v1;
    float mt0 = (j0 < n) ? mt[v0] : 0.f;
    float mt1 = (j1 < n) ? mt[v1] : 0.f;
    const unsigned short* bp0 = Etb + (size_t)v0*256 + q*8;
    const unsigned short* bp1 = Etb + (size_t)v1*256 + q*8;
    f32x4 acc[2][2];
    #pragma unroll
    for (int mi = 0; mi < 2; ++mi)
      #pragma unroll
      for (int ni = 0; ni < 2; ++ni) acc[mi][ni] = (f32x4){0.f,0.f,0.f,0.f};
    #pragma unroll
    for (int kt = 0; kt < 8; ++kt){
      bf16x8 b0 = *(const bf16x8*)(bp0 + kt*32);
      bf16x8 b1 = *(const bf16x8*)(bp1 + kt*32);
      acc[0][0] = mfma16(af0[kt], b0, acc[0][0]);
      acc[0][1] = mfma16(af0[kt], b1, acc[0][1]);
      acc[1][0] = mfma16(af1[kt], b0, acc[1][0]);
      acc[1][1] = mfma16(af1[kt], b1, acc[1][1]);
    }
    #pragma unroll
    for (int mi = 0; mi < 2; ++mi){
      #pragma unroll
      for (int r = 0; r < 4; ++r){
        int row = mi*16 + q*4 + r;
        float l0 = (j0 < n) ? (__logf(acc[mi][0][r]) + mpl[row] + mt0) : -1e30f;
        float l1 = (j1 < n) ? (__logf(acc[mi][1][r]) + mpl[row] + mt1) : -1e30f;
        lg[u][mi][0][r] = l0;
        lg[u][mi][1][r] = l1;
        float mv = fmaxf(l0, l1);
        #pragma unroll
        for (int d = 1; d < 16; d <<= 1) mv = fmaxf(mv, __shfl_xor(mv, d));
        float se = __expf(l0 - mv) + __expf(l1 - mv);
        #pragma unroll
        for (int d = 1; d < 16; d <<= 1) se += __shfl_xor(se, d);
        if (m16 == 0){ mtile[t][row] = mv; stile[t][row] = se; }
      }
    }
  }
  __syncthreads();
  if (tid < 32){
    float gm = -1e30f;
    for (int t = 0; t < nt; ++t) gm = fmaxf(gm, mtile[t][tid]);
    float gs = 0.f;
    for (int t = 0; t < nt; ++t) gs += stile[t][tid]*__expf(mtile[t][tid] - gm);
    denl[tid] = gm + __logf(gs);
  }
  __syncthreads();
  #pragma unroll
  for (int u = 0; u < 2; ++u){
    int t = w + u*4;
    if (t >= nt) continue;
    #pragma unroll
    for (int ni = 0; ni < 2; ++ni){
      int j = t*32 + ni*16 + m16;
      if (j >= n) continue;
      float* outp = emit_col + (size_t)vj[u][ni]*32;
      #pragma unroll
      for (int mi = 0; mi < 2; ++mi)
        #pragma unroll
        for (int r = 0; r < 4; ++r){
          int row = mi*16 + q*4 + r;
          outp[row] = lg[u][mi][ni][r] - denl[row];
        }
    }
  }
}

// ===========================================================================
// 32x32 product helpers
__device__ inline void prod_acc(const float* __restrict__ L0, const float* __restrict__ L1,
                                f32x4 acc[2][2], int ln)
{
  int m16 = ln & 15, q = ln >> 4;
  bf16x8 af[2], bfv[2];
  #pragma unroll
  for (int mi = 0; mi < 2; ++mi){
    const float* p = L0 + (mi*16 + m16)*MST + q*8;
    u16x8 u;
    #pragma unroll
    for (int jj = 0; jj < 8; ++jj) u[jj] = f2bf(p[jj]);
    af[mi] = __builtin_bit_cast(bf16x8, u);
  }
  #pragma unroll
  for (int ni = 0; ni < 2; ++ni){
    u16x8 u;
    #pragma unroll
    for (int jj = 0; jj < 8; ++jj) u[jj] = f2bf(L1[(q*8 + jj)*MST + ni*16 + m16]);
    bfv[ni] = __builtin_bit_cast(bf16x8, u);
  }
  #pragma unroll
  for (int mi = 0; mi < 2; ++mi)
    #pragma unroll
    for (int ni = 0; ni < 2; ++ni) acc[mi][ni] = mfma16(af[mi], bfv[ni], acc[mi][ni]);
}

__device__ inline void wave_norm_store(f32x4 acc[2][2], float* outp,
                                       float sIn, float* sOut, int ln)
{
  int m16 = ln & 15, q = ln >> 4;
  float mx = 0.f;
  #pragma unroll
  for (int mi = 0; mi < 2; ++mi)
    #pragma unroll
    for (int ni = 0; ni < 2; ++ni)
      #pragma unroll
      for (int r = 0; r < 4; ++r) mx = fmaxf(mx, acc[mi][ni][r]);
  #pragma unroll
  for (int d = 1; d < 64; d <<= 1) mx = fmaxf(mx, __shfl_xor(mx, d));
  float inv = 1.0f/mx;
  #pragma unroll
  for (int mi = 0; mi < 2; ++mi)
    #pragma unroll
    for (int ni = 0; ni < 2; ++ni)
      #pragma unroll
      for (int r = 0; r < 4; ++r)
        outp[(mi*16 + q*4 + r)*MST + ni*16 + m16] = acc[mi][ni][r]*inv;
  if (ln == 0) *sOut = sIn + __logf(mx);
}

__device__ inline void norm_store_g16(f32x4 acc[2][2], unsigned short* outp,
                                      float sIn, float* sOutG, int ln)
{
  int m16 = ln & 15, q = ln >> 4;
  float mx = 0.f;
  #pragma unroll
  for (int mi = 0; mi < 2; ++mi)
    #pragma unroll
    for (int ni = 0; ni < 2; ++ni)
      #pragma unroll
      for (int r = 0; r < 4; ++r) mx = fmaxf(mx, acc[mi][ni][r]);
  #pragma unroll
  for (int d = 1; d < 64; d <<= 1) mx = fmaxf(mx, __shfl_xor(mx, d));
  float inv = 1.0f/mx;
  #pragma unroll
  for (int mi = 0; mi < 2; ++mi)
    #pragma unroll
    for (int ni = 0; ni < 2; ++ni)
      #pragma unroll
      for (int r = 0; r < 4; ++r)
        outp[(mi*16 + q*4 + r)*32 + ni*16 + m16] = f2bf(acc[mi][ni][r]*inv);
  if (ln == 0) *sOutG = sIn + __logf(mx);
}

__device__ inline void prod32(const float* L0, const float* L1, float* outp,
                              float sIn, float* sOut, int ln)
{
  f32x4 acc[2][2];
  #pragma unroll
  for (int mi = 0; mi < 2; ++mi)
    #pragma unroll
    for (int ni = 0; ni < 2; ++ni) acc[mi][ni] = (f32x4){0.f,0.f,0.f,0.f};
  prod_acc(L0, L1, acc, ln);
  wave_norm_store(acc, outp, sIn, sOut, ln);
}

// ===========================================================================
// k_chunk: chunk tree (0..511), 8 waves, 1 leaf/wave | fx L3 (512..543)
__global__ __launch_bounds__(512) void k_chunk(
  const unsigned short* __restrict__ Eab, const unsigned short* __restrict__ Ebp,
  const float* __restrict__ emit_col, const float* __restrict__ denInv,
  const int* __restrict__ text, const int* __restrict__ w2s,
  unsigned short* __restrict__ Gm, float* __restrict__ Gs,
  const float* __restrict__ sw, const float* __restrict__ sb,
  float* __restrict__ Afx)
{
  __shared__ float bufL[8][32*MST];
  __shared__ float bufN[4][32*MST];
  __shared__ float sL[8], sN[4];
  int bx = blockIdx.x;
  int tid = threadIdx.x;
  if (bx >= 512){
    if (tid < 256){
      int j = bx - 512;
      float xh[8];
      #pragma unroll
      for (int i = 0; i < 8; ++i){
        int h = 8*j + i;
        float x0 = Afx[h] + sb[h];
        xh[i] = x0 + fmaxf(Afx[512 + h] + sb[512 + h], 0.f);
      }
      fx_accum(sw + 3*65536, xh, j, Afx + 768);
    }
    return;
  }
  int b = bx >> 5, ch = bx & 31;
  int w = tid >> 6, ln = tid & 63;
  int m16 = ln & 15, q = ln >> 4;
  // leaf w
  {
    int s = ch*8 + w;               // transition step t = s+1
    float* outp = bufL[w];
    if (s >= 255){
      for (int i = ln; i < 32*32; i += 64){
        int r = i >> 5, c = i & 31;
        outp[r*MST + c] = (r == c) ? 1.f : 0.f;
      }
      if (ln == 0) sL[w] = 0.f;
    } else {
      int vp = text[b*256 + s], vc = text[b*256 + s + 1];
      int bp = w2s[vp*32], bq = w2s[vc*32];
      const unsigned short* a0 = Eab + (size_t)(bp + m16)*256 + q*8;
      const unsigned short* b0 = Ebp + (size_t)(bq + m16)*256 + q*8;
      f32x4 acc[2][2];
      #pragma unroll
      for (int mi = 0; mi < 2; ++mi)
        #pragma unroll
        for (int ni = 0; ni < 2; ++ni) acc[mi][ni] = (f32x4){0.f,0.f,0.f,0.f};
      #pragma unroll
      for (int kt = 0; kt < 8; ++kt){
        bf16x8 a_0 = *(const bf16x8*)(a0 + kt*32);
        bf16x8 a_1 = *(const bf16x8*)(a0 + 16*256 + kt*32);
        bf16x8 b_0 = *(const bf16x8*)(b0 + kt*32);
        bf16x8 b_1 = *(const bf16x8*)(b0 + 16*256 + kt*32);
        acc[0][0] = mfma16(a_0, b_0, acc[0][0]);
        acc[0][1] = mfma16(a_0, b_1, acc[0][1]);
        acc[1][0] = mfma16(a_1, b_0, acc[1][0]);
        acc[1][1] = mfma16(a_1, b_1, acc[1][1]);
      }
      float e0 = __expf(emit_col[(size_t)vc*32 + m16]);
      float e1 = __expf(emit_col[(size_t)vc*32 + 16 + m16]);
      #pragma unroll
      for (int mi = 0; mi < 2; ++mi)
        #pragma unroll
        for (int r = 0; r < 4; ++r){
          float dn = denInv[bp + mi*16 + q*4 + r];
          acc[mi][0][r] *= e0*dn;
          acc[mi][1][r] *= e1*dn;
        }
      wave_norm_store(acc, outp, 0.f, &sL[w], ln);
    }
  }
  __syncthreads();
  if (w < 4) prod32(bufL[2*w], bufL[2*w+1], bufN[w], sL[2*w] + sL[2*w+1], &sN[w], ln);
  __syncthreads();
  if (w < 2) prod32(bufN[2*w], bufN[2*w+1], bufL[w], sN[2*w] + sN[2*w+1], &sL[w], ln);
  __syncthreads();
  if (w == 0){
    f32x4 acc[2][2];
    #pragma unroll
    for (int mi = 0; mi < 2; ++mi)
      #pragma unroll
      for (int ni = 0; ni < 2; ++ni) acc[mi][ni] = (f32x4){0.f,0.f,0.f,0.f};
    prod_acc(bufL[0], bufL[1], acc, ln);
    norm_store_g16(acc, Gm + (size_t)bx*1024, sL[0] + sL[1], Gs + bx, ln);
  }
}

// ===========================================================================
__device__ inline void load_mat16(const unsigned short* __restrict__ g,
                                  float* __restrict__ d, int ln){
  #pragma unroll
  for (int p = 0; p < 16; ++p){
    int idx = p*64 + ln;
    int r = idx >> 5, c = idx & 31;
    d[r*MST + c] = bf2f(g[idx]);
  }
}

// k_root: fx L4+proj GEMVs in-block -> eafx; 8 waves x 4-mat reduce; alpha0.
__global__ __launch_bounds__(512) void k_root(
  const unsigned short* __restrict__ Gm, const float* __restrict__ Gs,
  const float* __restrict__ Afx, const float* __restrict__ sb,
  const float* __restrict__ sw, const float* __restrict__ proj,
  const float* __restrict__ S,
  const unsigned short* __restrict__ Ebp, const float* __restrict__ emit_col,
  const int* __restrict__ text, const int* __restrict__ w2s, float* __restrict__ out)
{
  __shared__ float W[8][3][32*MST];
  __shared__ float sW[8], sT[1];
  __shared__ float eafx[256], sX2[256], sH[256];
  __shared__ float gpart[2][256];
  __shared__ float red[4];
  int b = blockIdx.x;
  int tid = threadIdx.x;
  int w = tid >> 6, ln = tid & 63;
  int t = tid & 255, u = tid >> 8;
  if (tid < 256){
    float x0 = Afx[tid] + sb[tid];
    sX2[tid] = x0 + fmaxf(Afx[512 + tid] + sb[512 + tid], 0.f);
    sH[tid]  = fmaxf(Afx[768 + tid] + sb[768 + tid], 0.f);
  }
  __syncthreads();
  {
    float a = 0.f;
    const float* Wp = sw + 4*65536 + (size_t)(128*u)*256 + t;
    #pragma unroll 8
    for (int h = 0; h < 128; ++h) a = fmaf(sH[128*u + h], Wp[(size_t)h*256], a);
    gpart[u][t] = a;
  }
  __syncthreads();
  if (tid < 256){
    float A4 = gpart[0][t] + gpart[1][t];
    float x4 = sX2[t] + fmaxf(A4 + sb[1024 + t], 0.f);
    sX2[t] = x4;
    float v2 = x4*x4;
    #pragma unroll
    for (int d = 1; d < 64; d <<= 1) v2 += __shfl_xor(v2, d);
    if ((t & 63) == 0) red[t >> 6] = v2;
  }
  __syncthreads();
  float nx = red[0] + red[1] + red[2] + red[3];
  {
    float a = 0.f;
    const float* Pp = proj + (size_t)(128*u)*256 + t;
    #pragma unroll 8
    for (int h = 0; h < 128; ++h) a = fmaf(sX2[128*u + h], Pp[(size_t)h*256], a);
    gpart[u][t] = a;
  }
  __syncthreads();
  float pxv = 0.f;
  if (tid < 256){
    pxv = gpart[0][t] + gpart[1][t] - 0.5f*nx;
    float m2 = pxv;
    #pragma unroll
    for (int d = 1; d < 64; d <<= 1) m2 = fmaxf(m2, __shfl_xor(m2, d));
    if ((t & 63) == 0) red[t >> 6] = m2;
  }
  __syncthreads();
  float m2g = fmaxf(fmaxf(red[0], red[1]), fmaxf(red[2], red[3]));
  if (tid < 256) eafx[t] = __expf(pxv - m2g);
  __syncthreads();
  // ---- chunk-matrix tree ----
  const unsigned short* G = Gm + ((size_t)(b*32 + w*4))*1024;
  const float* gs = Gs + b*32 + w*4;
  load_mat16(G,        W[w][0], ln);
  load_mat16(G + 1024, W[w][1], ln);
  prod32(W[w][0], W[w][1], W[w][2], gs[0] + gs[1], &sW[w], ln);
  load_mat16(G + 2048, W[w][0], ln);
  prod32(W[w][2], W[w][0], W[w][1], sW[w] + gs[2], &sW[w], ln);
  load_mat16(G + 3072, W[w][0], ln);
  prod32(W[w][1], W[w][0], W[w][2], sW[w] + gs[3], &sW[w], ln);
  __syncthreads();
  if (w == 0){
    float sAcc = sW[0];
    const float* cur = W[0][2];
    int dsel = 0;
    for (int j = 1; j < 8; ++j){
      float* dst = dsel ? W[0][1] : W[0][0];
      prod32(cur, W[j][2], dst, sAcc + sW[j], &sT[0], ln);
      sAcc = sT[0];
      cur = dst;
      dsel ^= 1;
    }
    float part = 0.f;
    for (int d = ln; d < 256; d += 64) part = fmaf(eafx[d], S[d], part);
    #pragma unroll
    for (int d2 = 1; d2 < 64; d2 <<= 1) part += __shfl_xor(part, d2);
    float dfx = part;
    int v0 = text[b*256];
    int k0 = w2s[v0*32];
    int j = ln & 31, h = ln >> 5;
    const unsigned short* er = Ebp + (size_t)(k0 + j)*256;
    float dot = 0.f;
    for (int d = h*128; d < h*128 + 128; ++d)
      dot = fmaf(eafx[d], bf2f(er[d]), dot);
    dot += __shfl_xor(dot, 32);
    float z0 = __logf(dot) + emit_col[(size_t)v0*32 + j];
    float mz = z0;
    #pragma unroll
    for (int d2 = 1; d2 < 32; d2 <<= 1) mz = fmaxf(mz, __shfl_xor(mz, d2));
    float an = __expf(z0 - mz);
    float cs = 0.f;
    for (int i = h*16; i < h*16 + 16; ++i)
      cs = fmaf(__shfl(an, i), cur[i*MST + j], cs);
    cs += __shfl_xor(cs, 32);
    float tot = cs;
    #pragma unroll
    for (int d2 = 1; d2 < 32; d2 <<= 1) tot += __shfl_xor(tot, d2);
    if (ln == 0) out[b] = __logf(tot) + mz + sAcc - __logf(dfx);
  }
}

// ===========================================================================
extern "C" void kernel_launch(void* const* d_in, const int* in_sizes, int n_in,
                              void* d_out, int out_size, void* d_ws, size_t ws_size,
                              hipStream_t stream)
{
  (void)in_sizes; (void)n_in; (void)out_size; (void)ws_size;
  const int*   text      = (const int*)  d_in[0];
  const float* start_emb = (const float*)d_in[1];
  const float* start_w   = (const float*)d_in[2];
  const float* start_b   = (const float*)d_in[3];
  const float* state_emb = (const float*)d_in[4];
  const float* next_emb  = (const float*)d_in[5];
  const float* pre_emb   = (const float*)d_in[6];
  const float* term_w    = (const float*)d_in[7];
  const float* term_b    = (const float*)d_in[8];
  const float* term_emb  = (const float*)d_in[9];
  const float* proj      = (const float*)d_in[10];
  const int*   w2s       = (const int*)  d_in[11];
  float* out = (float*)d_out;

  char* base = (char*)d_ws;
  size_t off = 0;
  auto alloc = [&](size_t bytes)->char*{
    char* p = base + off;
    off += (bytes + 255) & ~(size_t)255;
    return p;
  };
  // zero-init region: cnt | Afx | S (contiguous)
  int*   cnt = (int*)  alloc(128*4);          // 512 B
  float* Afx = (float*)alloc(4*256*4);        // 4096 B
  float* S   = (float*)alloc(256*4);          // 1024 B
  unsigned short* projT = (unsigned short*)alloc((size_t)65536*2);
  unsigned short* WT    = (unsigned short*)alloc((size_t)4*65536*2);
  unsigned short* Epb = (unsigned short*)alloc((size_t)C_*256*2);
  float* mpp  = (float*)alloc((size_t)C_*4);
  unsigned short* Etb = (unsigned short*)alloc((size_t)V_*256*2);
  float* mt   = (float*)alloc((size_t)V_*4);
  unsigned short* Eab = (unsigned short*)alloc((size_t)C_*256*2);
  unsigned short* Ebp = (unsigned short*)alloc((size_t)C_*256*2);
  float* maS  = (float*)alloc((size_t)C_*4);
  float* denInv = (float*)alloc((size_t)C_*4);
  int* list = (int*)alloc((size_t)128*CAP_*4);
  float* emit_col = (float*)alloc((size_t)V_*32*4);
  unsigned short* Gm = (unsigned short*)alloc((size_t)512*1024*2);
  float* Gs = (float*)alloc((size_t)512*4);

  (void)hipMemsetAsync(cnt, 0, 512 + 4096 + 1024, stream);

  k_prep<<<1352, 256, 0, stream>>>(proj, term_w, projT, WT, w2s, cnt, list,
                                   start_emb, start_w, Afx);
  k_stageB<<<729, 256, 0, stream>>>(pre_emb, WT, term_b, projT, Epb, mpp,
                                    next_emb, Ebp, S, term_emb, Etb, mt,
                                    start_w, start_b, Afx,
                                    state_emb, Eab, maS);
  k_stageC<<<224, 256, 0, stream>>>(Epb, mpp, Etb, mt, cnt, list, emit_col,
                                    Eab, S, denInv, start_w, start_b, Afx);
  k_chunk<<<544, 512, 0, stream>>>(Eab, Ebp, emit_col, denInv, text, w2s,
                                   Gm, Gs, start_w, start_b, Afx);
  k_root<<<16, 512, 0, stream>>>(Gm, Gs, Afx, start_b, start_w, proj, S,
                                 Ebp, emit_col, text, w2s, out);
}